// Round 1
// baseline (6546.280 us; speedup 1.0000x reference)
//
#include <hip/hip_runtime.h>
#include <math.h>

#define Bc 32
#define Tc 128
#define TYc 64
#define Ec 512
#define Hc 512
#define Vc 32000
#define HHc 256

static __device__ __forceinline__ float sigm(float x) { return 1.0f / (1.0f + expf(-x)); }

// ---------------- zero init ----------------
__global__ void k_zero(float* __restrict__ p, int n) {
    int i = blockIdx.x * 256 + threadIdx.x;
    if (i < n) p[i] = 0.0f;
}

// ---------------- pad-aware reverse scatter ----------------
__global__ void k_rev(const int* __restrict__ x, const float* __restrict__ xm, int* __restrict__ xb) {
    int b = blockIdx.x, tid = threadIdx.x;  // 128 threads
    __shared__ float r[128];
    r[tid] = xm[b * Tc + tid];
    __syncthreads();
    for (int o = 64; o > 0; o >>= 1) { if (tid < o) r[tid] += r[tid + o]; __syncthreads(); }
    int pad = Tc - (int)(r[0] + 0.5f);
    xb[b * Tc + tid] = 0;
    __syncthreads();
    int rev = Tc - 1 - tid - pad;
    if (rev < 0) rev = 0;
    xb[b * Tc + rev] = x[b * Tc + tid];
}

// ---------------- embedding gather (x, x_back, y) ----------------
__global__ void k_embed(const int* __restrict__ x, const int* __restrict__ xb, const int* __restrict__ y,
                        const float* __restrict__ emb, float* __restrict__ xe, float* __restrict__ xbe,
                        float* __restrict__ ye) {
    int r = blockIdx.x;
    int tid = threadIdx.x;  // 128 threads, 4 floats each (float4)
    int tok;
    float* dst;
    if (r < Bc * Tc) { tok = x[r]; dst = xe + (size_t)r * Ec; }
    else if (r < 2 * Bc * Tc) { int rr = r - Bc * Tc; tok = xb[rr]; dst = xbe + (size_t)rr * Ec; }
    else { int rr = r - 2 * Bc * Tc; tok = y[rr]; dst = ye + (size_t)rr * Ec; }
    const float4* src = (const float4*)(emb + (size_t)tok * Ec);
    ((float4*)dst)[tid] = src[tid];
}

// ---------------- generic NT GEMM: C[m,n] = sum_k A[m,k]*W[n,k] + bias ----------------
// A (M,K) row-major, W (N,K) row-major. M,N mult of 64, K mult of 16.
__global__ __launch_bounds__(256) void k_gemm_nt(const float* __restrict__ A, const float* __restrict__ W,
                                                 const float* __restrict__ bias1, const float* __restrict__ bias2,
                                                 float* __restrict__ C, int M, int N, int K) {
    __shared__ float As[16][64];
    __shared__ float Bs[16][64];
    int tid = threadIdx.x;
    int m0 = blockIdx.y << 6;
    int n0 = blockIdx.x << 6;
    int lr = tid >> 2;         // staging row 0..63
    int lc = (tid & 3) << 2;   // staging k-offset 0,4,8,12
    const float* Ap = A + (size_t)(m0 + lr) * K + lc;
    const float* Wp = W + (size_t)(n0 + lr) * K + lc;
    int tx = tid & 15, ty = tid >> 4;
    float acc[4][4] = {{0.f}};
    for (int k0 = 0; k0 < K; k0 += 16) {
        float4 av = *(const float4*)(Ap + k0);
        float4 wv = *(const float4*)(Wp + k0);
        __syncthreads();
        As[lc + 0][lr] = av.x; As[lc + 1][lr] = av.y; As[lc + 2][lr] = av.z; As[lc + 3][lr] = av.w;
        Bs[lc + 0][lr] = wv.x; Bs[lc + 1][lr] = wv.y; Bs[lc + 2][lr] = wv.z; Bs[lc + 3][lr] = wv.w;
        __syncthreads();
#pragma unroll
        for (int k = 0; k < 16; ++k) {
            float a0 = As[k][(ty << 2) + 0], a1 = As[k][(ty << 2) + 1];
            float a2 = As[k][(ty << 2) + 2], a3 = As[k][(ty << 2) + 3];
            float b0 = Bs[k][(tx << 2) + 0], b1 = Bs[k][(tx << 2) + 1];
            float b2 = Bs[k][(tx << 2) + 2], b3 = Bs[k][(tx << 2) + 3];
            acc[0][0] += a0 * b0; acc[0][1] += a0 * b1; acc[0][2] += a0 * b2; acc[0][3] += a0 * b3;
            acc[1][0] += a1 * b0; acc[1][1] += a1 * b1; acc[1][2] += a1 * b2; acc[1][3] += a1 * b3;
            acc[2][0] += a2 * b0; acc[2][1] += a2 * b1; acc[2][2] += a2 * b2; acc[2][3] += a2 * b3;
            acc[3][0] += a3 * b0; acc[3][1] += a3 * b1; acc[3][2] += a3 * b2; acc[3][3] += a3 * b3;
        }
    }
#pragma unroll
    for (int i = 0; i < 4; ++i) {
        int m = m0 + (ty << 2) + i;
#pragma unroll
        for (int j = 0; j < 4; ++j) {
            int n = n0 + (tx << 2) + j;
            float bs = (bias1 ? bias1[n] : 0.f) + (bias2 ? bias2[n] : 0.f);
            C[(size_t)m * N + n] = acc[i][j] + bs;
        }
    }
}

// ---------------- encoder step (both directions via blockIdx.z) ----------------
__global__ __launch_bounds__(256) void k_enc_step(
    const float* __restrict__ gxf, const float* __restrict__ gxb,
    const float* __restrict__ whf, const float* __restrict__ whb,
    const float* __restrict__ hfp, const float* __restrict__ cfp, float* __restrict__ hfn, float* __restrict__ cfn,
    const float* __restrict__ hbp, const float* __restrict__ cbp, float* __restrict__ hbn, float* __restrict__ cbn,
    float* __restrict__ hid, float* __restrict__ cel, int t) {
    int dir = blockIdx.z;
    const float* gx = dir ? gxb : gxf;
    const float* wh = dir ? whb : whf;
    const float* hp = dir ? hbp : hfp;
    const float* cp = dir ? cbp : cfp;
    float* hn = dir ? hbn : hfn;
    float* cn = dir ? cbn : cfn;
    int hoff = dir ? HHc : 0;
    int b = blockIdx.y;
    int chunk = blockIdx.x;
    int tid = threadIdx.x;
    __shared__ float hs[HHc];
    __shared__ float gv[4][64];
    hs[tid] = hp[b * HHc + tid];
    __syncthreads();
    int gate = tid >> 6;
    int jj = (chunk << 6) + (tid & 63);
    int n = gate * HHc + jj;
    const float* w = wh + (size_t)n * HHc;
    float s = gx[(size_t)(b * Tc + t) * (4 * HHc) + n];
#pragma unroll 8
    for (int k = 0; k < HHc; k += 4) {
        float4 wv = *(const float4*)(w + k);
        s += wv.x * hs[k] + wv.y * hs[k + 1] + wv.z * hs[k + 2] + wv.w * hs[k + 3];
    }
    gv[gate][tid & 63] = s;
    __syncthreads();
    if (tid < 64) {
        int j = (chunk << 6) + tid;
        float c = sigm(gv[1][tid]) * cp[b * HHc + j] + sigm(gv[0][tid]) * tanhf(gv[2][tid]);
        float h = sigm(gv[3][tid]) * tanhf(c);
        hn[b * HHc + j] = h;
        cn[b * HHc + j] = c;
        size_t o = (size_t)(b * Tc + t) * Hc + hoff + j;
        hid[o] = h;
        cel[o] = c;
    }
}

// ---------------- mean over T ----------------
__global__ void k_mean(const float* __restrict__ hid, const float* __restrict__ cel,
                       float* __restrict__ dh, float* __restrict__ dc) {
    int b = blockIdx.x, tid = threadIdx.x;  // 256
    for (int j = tid; j < Hc; j += 256) {
        float sh = 0.f, sc_ = 0.f;
        for (int t = 0; t < Tc; ++t) {
            size_t o = (size_t)(b * Tc + t) * Hc + j;
            sh += hid[o];
            sc_ += cel[o];
        }
        dh[b * Hc + j] = sh * (1.0f / Tc);
        dc[b * Hc + j] = sc_ * (1.0f / Tc);
    }
}

// ---------------- decoder LSTM step ----------------
__global__ __launch_bounds__(256) void k_dec_step(const float* __restrict__ gy, const float* __restrict__ whd,
                                                  const float* __restrict__ hprev, int hstride,
                                                  const float* __restrict__ cp, float* __restrict__ cn,
                                                  float* __restrict__ outH, int t) {
    int b = blockIdx.y;
    int chunk = blockIdx.x;
    int tid = threadIdx.x;
    __shared__ float hs[Hc];
    __shared__ float gv[4][64];
    hs[tid] = hprev[(size_t)b * hstride + tid];
    hs[tid + 256] = hprev[(size_t)b * hstride + tid + 256];
    __syncthreads();
    int gate = tid >> 6;
    int jj = (chunk << 6) + (tid & 63);
    int n = gate * Hc + jj;
    const float* w = whd + (size_t)n * Hc;
    float s = gy[(size_t)(b * TYc + t) * (4 * Hc) + n];
#pragma unroll 8
    for (int k = 0; k < Hc; k += 4) {
        float4 wv = *(const float4*)(w + k);
        s += wv.x * hs[k] + wv.y * hs[k + 1] + wv.z * hs[k + 2] + wv.w * hs[k + 3];
    }
    gv[gate][tid & 63] = s;
    __syncthreads();
    if (tid < 64) {
        int j = (chunk << 6) + tid;
        float c = sigm(gv[1][tid]) * cp[b * Hc + j] + sigm(gv[0][tid]) * tanhf(gv[2][tid]);
        float h = sigm(gv[3][tid]) * tanhf(c);
        cn[b * Hc + j] = c;
        outH[(size_t)(b * TYc + t) * (2 * Hc) + j] = h;
    }
}

// ---------------- attention step ----------------
__global__ __launch_bounds__(128) void k_attn(const float* __restrict__ hid, float* __restrict__ outH, int t) {
    int b = blockIdx.x, tid = threadIdx.x;  // 128
    __shared__ float hq[Hc];
    __shared__ float sc[Tc];
    __shared__ float red[128];
    const float* hrow = outH + (size_t)(b * TYc + t) * (2 * Hc);
    for (int k = tid; k < Hc; k += 128) hq[k] = hrow[k];
    __syncthreads();
    const float* hr = hid + (size_t)(b * Tc + tid) * Hc;
    float s = 0.f;
#pragma unroll 8
    for (int k = 0; k < Hc; k += 4) {
        float4 hv = *(const float4*)(hr + k);
        s += hv.x * hq[k] + hv.y * hq[k + 1] + hv.z * hq[k + 2] + hv.w * hq[k + 3];
    }
    red[tid] = s;
    __syncthreads();
    for (int o = 64; o > 0; o >>= 1) { if (tid < o) red[tid] = fmaxf(red[tid], red[tid + o]); __syncthreads(); }
    float mx = red[0];
    __syncthreads();
    float e = expf(s - mx);
    sc[tid] = e;
    red[tid] = e;
    __syncthreads();
    for (int o = 64; o > 0; o >>= 1) { if (tid < o) red[tid] += red[tid + o]; __syncthreads(); }
    float inv = 1.0f / red[0];
    for (int j = tid; j < Hc; j += 128) {
        float acc = 0.f;
        for (int tt = 0; tt < Tc; ++tt) acc += sc[tt] * hid[(size_t)(b * Tc + tt) * Hc + j];
        outH[(size_t)(b * TYc + t) * (2 * Hc) + Hc + j] = acc * inv;
    }
}

// ---------------- in-place log-softmax over V ----------------
__global__ __launch_bounds__(256) void k_logsm(float* __restrict__ P) {
    int row = blockIdx.x, tid = threadIdx.x;
    float* p = P + (size_t)row * Vc;
    __shared__ float red[256];
    float m = -1e30f;
    for (int i = tid; i < Vc; i += 256) m = fmaxf(m, p[i]);
    red[tid] = m;
    __syncthreads();
    for (int o = 128; o > 0; o >>= 1) { if (tid < o) red[tid] = fmaxf(red[tid], red[tid + o]); __syncthreads(); }
    float mx = red[0];
    __syncthreads();
    float s = 0.f;
    for (int i = tid; i < Vc; i += 256) s += expf(p[i] - mx);
    red[tid] = s;
    __syncthreads();
    for (int o = 128; o > 0; o >>= 1) { if (tid < o) red[tid] += red[tid + o]; __syncthreads(); }
    float lse = mx + logf(red[0]);
    for (int i = tid; i < Vc; i += 256) p[i] -= lse;
}

extern "C" void kernel_launch(void* const* d_in, const int* in_sizes, int n_in,
                              void* d_out, int out_size, void* d_ws, size_t ws_size,
                              hipStream_t stream) {
    const int* x = (const int*)d_in[0];
    const float* xm = (const float*)d_in[1];
    const int* y = (const int*)d_in[2];
    const float* emb = (const float*)d_in[3];
    const float* w_ih_f = (const float*)d_in[4];
    const float* w_hh_f = (const float*)d_in[5];
    const float* b_ih_f = (const float*)d_in[6];
    const float* b_hh_f = (const float*)d_in[7];
    const float* w_ih_b = (const float*)d_in[8];
    const float* w_hh_b = (const float*)d_in[9];
    const float* b_ih_b = (const float*)d_in[10];
    const float* b_hh_b = (const float*)d_in[11];
    const float* w_ih_d = (const float*)d_in[12];
    const float* w_hh_d = (const float*)d_in[13];
    const float* b_ih_d = (const float*)d_in[14];
    const float* b_hh_d = (const float*)d_in[15];
    const float* W_out = (const float*)d_in[16];
    const float* b_out = (const float*)d_in[17];

    float* out = (float*)d_out;
    float* logp = out;                           // (B*TY, V)
    float* outH = out + (size_t)Bc * TYc * Vc;   // (B*TY, 2H) — final output region

    // Scratch arena lives inside the (huge) logp region; it is only clobbered
    // by the final logits GEMM, by which point all intermediates are dead.
    float* xe = out;                                // (B*T, E)
    float* xbe = xe + (size_t)Bc * Tc * Ec;         // (B*T, E)
    float* ye = xbe + (size_t)Bc * Tc * Ec;         // (B*TY, E)
    float* gf = ye + (size_t)Bc * TYc * Ec;         // (B*T, 4HH)
    float* gb = gf + (size_t)Bc * Tc * 4 * HHc;     // (B*T, 4HH)
    float* gd = gb + (size_t)Bc * Tc * 4 * HHc;     // (B*TY, 4H)
    float* hid = gd + (size_t)Bc * TYc * 4 * Hc;    // (B,T,H)
    float* cel = hid + (size_t)Bc * Tc * Hc;        // (B,T,H)
    float* st = cel + (size_t)Bc * Tc * Hc;         // encoder states x8
    float* hf0 = st;
    float* hf1 = hf0 + Bc * HHc;
    float* cf0 = hf1 + Bc * HHc;
    float* cf1 = cf0 + Bc * HHc;
    float* hb0 = cf1 + Bc * HHc;
    float* hb1 = hb0 + Bc * HHc;
    float* cb0 = hb1 + Bc * HHc;
    float* cb1 = cb0 + Bc * HHc;
    float* dh0 = cb1 + Bc * HHc;   // (B,H) decoder h init (= h_mean)
    float* dc0 = dh0 + Bc * Hc;    // decoder c ping
    float* dc1 = dc0 + Bc * Hc;    // decoder c pong
    int* xb = (int*)(dc1 + Bc * Hc);  // (B,T) reversed tokens

    (void)in_sizes; (void)n_in; (void)out_size; (void)d_ws; (void)ws_size;

    k_rev<<<Bc, 128, 0, stream>>>(x, xm, xb);
    k_zero<<<(8 * Bc * HHc + 255) / 256, 256, 0, stream>>>(st, 8 * Bc * HHc);
    k_embed<<<2 * Bc * Tc + Bc * TYc, 128, 0, stream>>>(x, xb, y, emb, xe, xbe, ye);

    // input-side gate GEMMs (bias folded: b_ih + b_hh)
    k_gemm_nt<<<dim3(4 * HHc / 64, Bc * Tc / 64), 256, 0, stream>>>(xe, w_ih_f, b_ih_f, b_hh_f, gf, Bc * Tc, 4 * HHc, Ec);
    k_gemm_nt<<<dim3(4 * HHc / 64, Bc * Tc / 64), 256, 0, stream>>>(xbe, w_ih_b, b_ih_b, b_hh_b, gb, Bc * Tc, 4 * HHc, Ec);
    k_gemm_nt<<<dim3(4 * Hc / 64, Bc * TYc / 64), 256, 0, stream>>>(ye, w_ih_d, b_ih_d, b_hh_d, gd, Bc * TYc, 4 * Hc, Ec);

    // encoder recurrence
    for (int t = 0; t < Tc; ++t) {
        const float* hfp = (t & 1) ? hf1 : hf0;
        const float* cfp = (t & 1) ? cf1 : cf0;
        const float* hbp = (t & 1) ? hb1 : hb0;
        const float* cbp = (t & 1) ? cb1 : cb0;
        float* hfn = (t & 1) ? hf0 : hf1;
        float* cfn = (t & 1) ? cf0 : cf1;
        float* hbn = (t & 1) ? hb0 : hb1;
        float* cbn = (t & 1) ? cb0 : cb1;
        k_enc_step<<<dim3(HHc / 64, Bc, 2), 256, 0, stream>>>(gf, gb, w_hh_f, w_hh_b,
                                                              hfp, cfp, hfn, cfn,
                                                              hbp, cbp, hbn, cbn, hid, cel, t);
    }

    k_mean<<<Bc, 256, 0, stream>>>(hid, cel, dh0, dc0);

    // decoder recurrence + attention
    for (int t = 0; t < TYc; ++t) {
        const float* hprev = (t == 0) ? dh0 : (outH + (size_t)(t - 1) * (2 * Hc));
        int hstride = (t == 0) ? Hc : TYc * 2 * Hc;
        const float* cp = (t & 1) ? dc1 : dc0;
        float* cn = (t & 1) ? dc0 : dc1;
        k_dec_step<<<dim3(Hc / 64, Bc), 256, 0, stream>>>(gd, w_hh_d, hprev, hstride, cp, cn, outH, t);
        k_attn<<<Bc, 128, 0, stream>>>(hid, outH, t);
    }

    // logits = outH @ W_out^T + b_out  (overwrites the scratch arena — OK, dead)
    k_gemm_nt<<<dim3(Vc / 64, Bc * TYc / 64), 256, 0, stream>>>(outH, W_out, b_out, nullptr, logp, Bc * TYc, Vc, 2 * Hc);
    k_logsm<<<Bc * TYc, 256, 0, stream>>>(logp);
}

// Round 2
// 4693.465 us; speedup vs baseline: 1.3948x; 1.3948x over previous
//
#include <hip/hip_runtime.h>
#include <math.h>

#define Bc 32
#define Tc 128
#define TYc 64
#define Ec 512
#define Hc 512
#define Vc 32000
#define HHc 256

typedef unsigned short u16;
typedef unsigned int u32;
typedef short bf16x8 __attribute__((ext_vector_type(8)));
typedef float f32x4 __attribute__((ext_vector_type(4)));

static __device__ __forceinline__ float sigm(float x) { return 1.0f / (1.0f + expf(-x)); }

static __device__ __forceinline__ u16 f2bf(float f) {
    u32 u = __float_as_uint(f);
    u += 0x7FFFu + ((u >> 16) & 1u);  // RNE
    return (u16)(u >> 16);
}

// ---------------- zero init ----------------
__global__ void k_zero(float* __restrict__ p, int n) {
    int i = blockIdx.x * 256 + threadIdx.x;
    if (i < n) p[i] = 0.0f;
}

// ---------------- pad-aware reverse scatter ----------------
__global__ void k_rev(const int* __restrict__ x, const float* __restrict__ xm, int* __restrict__ xb) {
    int b = blockIdx.x, tid = threadIdx.x;  // 128 threads
    __shared__ float r[128];
    r[tid] = xm[b * Tc + tid];
    __syncthreads();
    for (int o = 64; o > 0; o >>= 1) { if (tid < o) r[tid] += r[tid + o]; __syncthreads(); }
    int pad = Tc - (int)(r[0] + 0.5f);
    xb[b * Tc + tid] = 0;
    __syncthreads();
    int rev = Tc - 1 - tid - pad;
    if (rev < 0) rev = 0;
    xb[b * Tc + rev] = x[b * Tc + tid];
}

// ---------------- embedding gather (x, x_back, y) ----------------
__global__ void k_embed(const int* __restrict__ x, const int* __restrict__ xb, const int* __restrict__ y,
                        const float* __restrict__ emb, float* __restrict__ xe, float* __restrict__ xbe,
                        float* __restrict__ ye) {
    int r = blockIdx.x;
    int tid = threadIdx.x;  // 128 threads, 4 floats each (float4)
    int tok;
    float* dst;
    if (r < Bc * Tc) { tok = x[r]; dst = xe + (size_t)r * Ec; }
    else if (r < 2 * Bc * Tc) { int rr = r - Bc * Tc; tok = xb[rr]; dst = xbe + (size_t)rr * Ec; }
    else { int rr = r - 2 * Bc * Tc; tok = y[rr]; dst = ye + (size_t)rr * Ec; }
    const float4* src = (const float4*)(emb + (size_t)tok * Ec);
    ((float4*)dst)[tid] = src[tid];
}

// ---------------- fp32 NT GEMM (input-side gates + fallback) ----------------
__global__ __launch_bounds__(256) void k_gemm_nt(const float* __restrict__ A, const float* __restrict__ W,
                                                 const float* __restrict__ bias1, const float* __restrict__ bias2,
                                                 float* __restrict__ C, int M, int N, int K) {
    __shared__ float As[16][64];
    __shared__ float Bs[16][64];
    int tid = threadIdx.x;
    int m0 = blockIdx.y << 6;
    int n0 = blockIdx.x << 6;
    int lr = tid >> 2;
    int lc = (tid & 3) << 2;
    const float* Ap = A + (size_t)(m0 + lr) * K + lc;
    const float* Wp = W + (size_t)(n0 + lr) * K + lc;
    int tx = tid & 15, ty = tid >> 4;
    float acc[4][4] = {{0.f}};
    for (int k0 = 0; k0 < K; k0 += 16) {
        float4 av = *(const float4*)(Ap + k0);
        float4 wv = *(const float4*)(Wp + k0);
        __syncthreads();
        As[lc + 0][lr] = av.x; As[lc + 1][lr] = av.y; As[lc + 2][lr] = av.z; As[lc + 3][lr] = av.w;
        Bs[lc + 0][lr] = wv.x; Bs[lc + 1][lr] = wv.y; Bs[lc + 2][lr] = wv.z; Bs[lc + 3][lr] = wv.w;
        __syncthreads();
#pragma unroll
        for (int k = 0; k < 16; ++k) {
            float a0 = As[k][(ty << 2) + 0], a1 = As[k][(ty << 2) + 1];
            float a2 = As[k][(ty << 2) + 2], a3 = As[k][(ty << 2) + 3];
            float b0 = Bs[k][(tx << 2) + 0], b1 = Bs[k][(tx << 2) + 1];
            float b2 = Bs[k][(tx << 2) + 2], b3 = Bs[k][(tx << 2) + 3];
            acc[0][0] += a0 * b0; acc[0][1] += a0 * b1; acc[0][2] += a0 * b2; acc[0][3] += a0 * b3;
            acc[1][0] += a1 * b0; acc[1][1] += a1 * b1; acc[1][2] += a1 * b2; acc[1][3] += a1 * b3;
            acc[2][0] += a2 * b0; acc[2][1] += a2 * b1; acc[2][2] += a2 * b2; acc[2][3] += a2 * b3;
            acc[3][0] += a3 * b0; acc[3][1] += a3 * b1; acc[3][2] += a3 * b2; acc[3][3] += a3 * b3;
        }
    }
#pragma unroll
    for (int i = 0; i < 4; ++i) {
        int m = m0 + (ty << 2) + i;
#pragma unroll
        for (int j = 0; j < 4; ++j) {
            int n = n0 + (tx << 2) + j;
            float bs = (bias1 ? bias1[n] : 0.f) + (bias2 ? bias2[n] : 0.f);
            C[(size_t)m * N + n] = acc[i][j] + bs;
        }
    }
}

// ---------------- fp32 -> bf16 cast (W_out then outH, one grid) ----------------
__global__ void k_cast(const float* __restrict__ W, const float* __restrict__ Hh,
                       u16* __restrict__ Wb, u16* __restrict__ Ab, int nW, int nA) {
    int i = (blockIdx.x * 256 + threadIdx.x) * 4;
    if (i < nW) {
        float4 v = *(const float4*)(W + i);
        Wb[i + 0] = f2bf(v.x); Wb[i + 1] = f2bf(v.y); Wb[i + 2] = f2bf(v.z); Wb[i + 3] = f2bf(v.w);
    } else {
        int j = i - nW;
        if (j < nA) {
            float4 v = *(const float4*)(Hh + j);
            Ab[j + 0] = f2bf(v.x); Ab[j + 1] = f2bf(v.y); Ab[j + 2] = f2bf(v.z); Ab[j + 3] = f2bf(v.w);
        }
    }
}

// ---------------- bf16 MFMA NT GEMM: C[m,n] = A[m,:].W[n,:] + bias ----------------
// A (M,K) bf16 row-major, W (N,K) bf16 row-major. Tile 128x128, BK=32, 4 waves.
#define LDAp 40  // padded LDS row stride (bf16 elems): bank groups {0,20,8,28,16,4,24,12}
__global__ __launch_bounds__(256) void k_gemm_bf16(const u16* __restrict__ A, const u16* __restrict__ W,
                                                   const float* __restrict__ bias, float* __restrict__ C,
                                                   int M, int N, int K) {
    __shared__ u16 As[128 * LDAp];
    __shared__ u16 Bs[128 * LDAp];
    int tid = threadIdx.x;
    int m0 = blockIdx.y << 7;
    int n0 = blockIdx.x << 7;

    // staging coords: 256 threads cover 64 rows x 32 cols per round; 2 rounds
    int r4 = tid >> 2;          // 0..63
    int c8 = (tid & 3) << 3;    // 0,8,16,24
    const u16* Ag = A + (size_t)(m0 + r4) * K + c8;
    const u16* Wg = W + (size_t)(n0 + r4) * K + c8;
    u16* AsW = &As[r4 * LDAp + c8];
    u16* BsW = &Bs[r4 * LDAp + c8];

    // compute coords
    int wv = tid >> 6;
    int lane = tid & 63;
    int wm = (wv >> 1) << 6;    // 0 or 64
    int wn = (wv & 1) << 6;
    int lr = lane & 15;
    int kq = (lane >> 4) << 3;  // 0,8,16,24
    const u16* Ard = &As[(wm + lr) * LDAp + kq];
    const u16* Brd = &Bs[(wn + lr) * LDAp + kq];

    f32x4 acc[4][4];
#pragma unroll
    for (int i = 0; i < 4; ++i)
#pragma unroll
        for (int j = 0; j < 4; ++j) acc[i][j] = (f32x4){0.f, 0.f, 0.f, 0.f};

    for (int k0 = 0; k0 < K; k0 += 32) {
        uint4 a0 = *(const uint4*)(Ag + k0);
        uint4 a1 = *(const uint4*)(Ag + (size_t)64 * K + k0);
        uint4 b0 = *(const uint4*)(Wg + k0);
        uint4 b1 = *(const uint4*)(Wg + (size_t)64 * K + k0);
        __syncthreads();
        *(uint4*)AsW = a0;
        *(uint4*)(AsW + 64 * LDAp) = a1;
        *(uint4*)BsW = b0;
        *(uint4*)(BsW + 64 * LDAp) = b1;
        __syncthreads();
        bf16x8 af[4], bfr[4];
#pragma unroll
        for (int i = 0; i < 4; ++i) {
            af[i] = *(const bf16x8*)(Ard + i * 16 * LDAp);
            bfr[i] = *(const bf16x8*)(Brd + i * 16 * LDAp);
        }
#pragma unroll
        for (int i = 0; i < 4; ++i)
#pragma unroll
            for (int j = 0; j < 4; ++j)
                acc[i][j] = __builtin_amdgcn_mfma_f32_16x16x32_bf16(af[i], bfr[j], acc[i][j], 0, 0, 0);
    }

    int rq = (lane >> 4) << 2;  // row quad base in 16x16 tile
#pragma unroll
    for (int i = 0; i < 4; ++i) {
#pragma unroll
        for (int j = 0; j < 4; ++j) {
            int n = n0 + wn + j * 16 + lr;
            float bs = bias[n];
            size_t base = (size_t)(m0 + wm + i * 16 + rq) * N + n;
#pragma unroll
            for (int r = 0; r < 4; ++r)
                C[base + (size_t)r * N] = acc[i][j][r] + bs;
        }
    }
}

// ---------------- encoder step (both directions via blockIdx.z) ----------------
__global__ __launch_bounds__(256) void k_enc_step(
    const float* __restrict__ gxf, const float* __restrict__ gxb,
    const float* __restrict__ whf, const float* __restrict__ whb,
    const float* __restrict__ hfp, const float* __restrict__ cfp, float* __restrict__ hfn, float* __restrict__ cfn,
    const float* __restrict__ hbp, const float* __restrict__ cbp, float* __restrict__ hbn, float* __restrict__ cbn,
    float* __restrict__ hid, float* __restrict__ cel, int t) {
    int dir = blockIdx.z;
    const float* gx = dir ? gxb : gxf;
    const float* wh = dir ? whb : whf;
    const float* hp = dir ? hbp : hfp;
    const float* cp = dir ? cbp : cfp;
    float* hn = dir ? hbn : hfn;
    float* cn = dir ? cbn : cfn;
    int hoff = dir ? HHc : 0;
    int b = blockIdx.y;
    int chunk = blockIdx.x;
    int tid = threadIdx.x;
    __shared__ float hs[HHc];
    __shared__ float gv[4][64];
    hs[tid] = hp[b * HHc + tid];
    __syncthreads();
    int gate = tid >> 6;
    int jj = (chunk << 6) + (tid & 63);
    int n = gate * HHc + jj;
    const float* w = wh + (size_t)n * HHc;
    float s = gx[(size_t)(b * Tc + t) * (4 * HHc) + n];
#pragma unroll 8
    for (int k = 0; k < HHc; k += 4) {
        float4 wv = *(const float4*)(w + k);
        s += wv.x * hs[k] + wv.y * hs[k + 1] + wv.z * hs[k + 2] + wv.w * hs[k + 3];
    }
    gv[gate][tid & 63] = s;
    __syncthreads();
    if (tid < 64) {
        int j = (chunk << 6) + tid;
        float c = sigm(gv[1][tid]) * cp[b * HHc + j] + sigm(gv[0][tid]) * tanhf(gv[2][tid]);
        float h = sigm(gv[3][tid]) * tanhf(c);
        hn[b * HHc + j] = h;
        cn[b * HHc + j] = c;
        size_t o = (size_t)(b * Tc + t) * Hc + hoff + j;
        hid[o] = h;
        cel[o] = c;
    }
}

// ---------------- mean over T ----------------
__global__ void k_mean(const float* __restrict__ hid, const float* __restrict__ cel,
                       float* __restrict__ dh, float* __restrict__ dc) {
    int b = blockIdx.x, tid = threadIdx.x;  // 256
    for (int j = tid; j < Hc; j += 256) {
        float sh = 0.f, sc_ = 0.f;
        for (int t = 0; t < Tc; ++t) {
            size_t o = (size_t)(b * Tc + t) * Hc + j;
            sh += hid[o];
            sc_ += cel[o];
        }
        dh[b * Hc + j] = sh * (1.0f / Tc);
        dc[b * Hc + j] = sc_ * (1.0f / Tc);
    }
}

// ---------------- decoder LSTM step ----------------
__global__ __launch_bounds__(256) void k_dec_step(const float* __restrict__ gy, const float* __restrict__ whd,
                                                  const float* __restrict__ hprev, int hstride,
                                                  const float* __restrict__ cp, float* __restrict__ cn,
                                                  float* __restrict__ outH, int t) {
    int b = blockIdx.y;
    int chunk = blockIdx.x;
    int tid = threadIdx.x;
    __shared__ float hs[Hc];
    __shared__ float gv[4][64];
    hs[tid] = hprev[(size_t)b * hstride + tid];
    hs[tid + 256] = hprev[(size_t)b * hstride + tid + 256];
    __syncthreads();
    int gate = tid >> 6;
    int jj = (chunk << 6) + (tid & 63);
    int n = gate * Hc + jj;
    const float* w = whd + (size_t)n * Hc;
    float s = gy[(size_t)(b * TYc + t) * (4 * Hc) + n];
#pragma unroll 8
    for (int k = 0; k < Hc; k += 4) {
        float4 wv = *(const float4*)(w + k);
        s += wv.x * hs[k] + wv.y * hs[k + 1] + wv.z * hs[k + 2] + wv.w * hs[k + 3];
    }
    gv[gate][tid & 63] = s;
    __syncthreads();
    if (tid < 64) {
        int j = (chunk << 6) + tid;
        float c = sigm(gv[1][tid]) * cp[b * Hc + j] + sigm(gv[0][tid]) * tanhf(gv[2][tid]);
        float h = sigm(gv[3][tid]) * tanhf(c);
        cn[b * Hc + j] = c;
        outH[(size_t)(b * TYc + t) * (2 * Hc) + j] = h;
    }
}

// ---------------- attention step ----------------
__global__ __launch_bounds__(128) void k_attn(const float* __restrict__ hid, float* __restrict__ outH, int t) {
    int b = blockIdx.x, tid = threadIdx.x;  // 128
    __shared__ float hq[Hc];
    __shared__ float sc[Tc];
    __shared__ float red[128];
    const float* hrow = outH + (size_t)(b * TYc + t) * (2 * Hc);
    for (int k = tid; k < Hc; k += 128) hq[k] = hrow[k];
    __syncthreads();
    const float* hr = hid + (size_t)(b * Tc + tid) * Hc;
    float s = 0.f;
#pragma unroll 8
    for (int k = 0; k < Hc; k += 4) {
        float4 hv = *(const float4*)(hr + k);
        s += hv.x * hq[k] + hv.y * hq[k + 1] + hv.z * hq[k + 2] + hv.w * hq[k + 3];
    }
    red[tid] = s;
    __syncthreads();
    for (int o = 64; o > 0; o >>= 1) { if (tid < o) red[tid] = fmaxf(red[tid], red[tid + o]); __syncthreads(); }
    float mx = red[0];
    __syncthreads();
    float e = expf(s - mx);
    sc[tid] = e;
    red[tid] = e;
    __syncthreads();
    for (int o = 64; o > 0; o >>= 1) { if (tid < o) red[tid] += red[tid + o]; __syncthreads(); }
    float inv = 1.0f / red[0];
    for (int j = tid; j < Hc; j += 128) {
        float acc = 0.f;
        for (int tt = 0; tt < Tc; ++tt) acc += sc[tt] * hid[(size_t)(b * Tc + tt) * Hc + j];
        outH[(size_t)(b * TYc + t) * (2 * Hc) + Hc + j] = acc * inv;
    }
}

// ---------------- in-place log-softmax over V (online max+sum: 2 passes) ----------------
__global__ __launch_bounds__(256) void k_logsm(float* __restrict__ P) {
    int row = blockIdx.x, tid = threadIdx.x;
    float* p = P + (size_t)row * Vc;
    float m = -1e30f, s = 0.f;
    for (int i = tid; i < Vc; i += 256) {
        float v = p[i];
        float nm = fmaxf(m, v);
        s = s * expf(m - nm) + expf(v - nm);
        m = nm;
    }
    __shared__ float ms[256], ss[256];
    ms[tid] = m; ss[tid] = s;
    __syncthreads();
    for (int o = 128; o > 0; o >>= 1) {
        if (tid < o) {
            float m2 = ms[tid + o], s2 = ss[tid + o];
            float nm = fmaxf(ms[tid], m2);
            ss[tid] = ss[tid] * expf(ms[tid] - nm) + s2 * expf(m2 - nm);
            ms[tid] = nm;
        }
        __syncthreads();
    }
    float lse = ms[0] + logf(ss[0]);
    for (int i = tid; i < Vc; i += 256) p[i] -= lse;
}

extern "C" void kernel_launch(void* const* d_in, const int* in_sizes, int n_in,
                              void* d_out, int out_size, void* d_ws, size_t ws_size,
                              hipStream_t stream) {
    const int* x = (const int*)d_in[0];
    const float* xm = (const float*)d_in[1];
    const int* y = (const int*)d_in[2];
    const float* emb = (const float*)d_in[3];
    const float* w_ih_f = (const float*)d_in[4];
    const float* w_hh_f = (const float*)d_in[5];
    const float* b_ih_f = (const float*)d_in[6];
    const float* b_hh_f = (const float*)d_in[7];
    const float* w_ih_b = (const float*)d_in[8];
    const float* w_hh_b = (const float*)d_in[9];
    const float* b_ih_b = (const float*)d_in[10];
    const float* b_hh_b = (const float*)d_in[11];
    const float* w_ih_d = (const float*)d_in[12];
    const float* w_hh_d = (const float*)d_in[13];
    const float* b_ih_d = (const float*)d_in[14];
    const float* b_hh_d = (const float*)d_in[15];
    const float* W_out = (const float*)d_in[16];
    const float* b_out = (const float*)d_in[17];

    float* out = (float*)d_out;
    float* logp = out;                           // (B*TY, V)
    float* outH = out + (size_t)Bc * TYc * Vc;   // (B*TY, 2H) — final output region

    // Scratch arena inside logp region (dead by the time the logits GEMM writes it).
    float* xe = out;                                // (B*T, E)
    float* xbe = xe + (size_t)Bc * Tc * Ec;
    float* ye = xbe + (size_t)Bc * Tc * Ec;
    float* gf = ye + (size_t)Bc * TYc * Ec;
    float* gb = gf + (size_t)Bc * Tc * 4 * HHc;
    float* gd = gb + (size_t)Bc * Tc * 4 * HHc;
    float* hid = gd + (size_t)Bc * TYc * 4 * Hc;
    float* cel = hid + (size_t)Bc * Tc * Hc;
    float* st = cel + (size_t)Bc * Tc * Hc;
    float* hf0 = st;
    float* hf1 = hf0 + Bc * HHc;
    float* cf0 = hf1 + Bc * HHc;
    float* cf1 = cf0 + Bc * HHc;
    float* hb0 = cf1 + Bc * HHc;
    float* hb1 = hb0 + Bc * HHc;
    float* cb0 = hb1 + Bc * HHc;
    float* cb1 = cb0 + Bc * HHc;
    float* dh0 = cb1 + Bc * HHc;
    float* dc0 = dh0 + Bc * Hc;
    float* dc1 = dc0 + Bc * Hc;
    int* xb = (int*)(dc1 + Bc * Hc);

    (void)in_sizes; (void)n_in; (void)out_size;

    k_rev<<<Bc, 128, 0, stream>>>(x, xm, xb);
    k_zero<<<(8 * Bc * HHc + 255) / 256, 256, 0, stream>>>(st, 8 * Bc * HHc);
    k_embed<<<2 * Bc * Tc + Bc * TYc, 128, 0, stream>>>(x, xb, y, emb, xe, xbe, ye);

    // input-side gate GEMMs (bias folded: b_ih + b_hh)
    k_gemm_nt<<<dim3(4 * HHc / 64, Bc * Tc / 64), 256, 0, stream>>>(xe, w_ih_f, b_ih_f, b_hh_f, gf, Bc * Tc, 4 * HHc, Ec);
    k_gemm_nt<<<dim3(4 * HHc / 64, Bc * Tc / 64), 256, 0, stream>>>(xbe, w_ih_b, b_ih_b, b_hh_b, gb, Bc * Tc, 4 * HHc, Ec);
    k_gemm_nt<<<dim3(4 * Hc / 64, Bc * TYc / 64), 256, 0, stream>>>(ye, w_ih_d, b_ih_d, b_hh_d, gd, Bc * TYc, 4 * Hc, Ec);

    // encoder recurrence
    for (int t = 0; t < Tc; ++t) {
        const float* hfp = (t & 1) ? hf1 : hf0;
        const float* cfp = (t & 1) ? cf1 : cf0;
        const float* hbp = (t & 1) ? hb1 : hb0;
        const float* cbp = (t & 1) ? cb1 : cb0;
        float* hfn = (t & 1) ? hf0 : hf1;
        float* cfn = (t & 1) ? cf0 : cf1;
        float* hbn = (t & 1) ? hb0 : hb1;
        float* cbn = (t & 1) ? cb0 : cb1;
        k_enc_step<<<dim3(HHc / 64, Bc, 2), 256, 0, stream>>>(gf, gb, w_hh_f, w_hh_b,
                                                              hfp, cfp, hfn, cfn,
                                                              hbp, cbp, hbn, cbn, hid, cel, t);
    }

    k_mean<<<Bc, 256, 0, stream>>>(hid, cel, dh0, dc0);

    // decoder recurrence + attention
    for (int t = 0; t < TYc; ++t) {
        const float* hprev = (t == 0) ? dh0 : (outH + (size_t)(t - 1) * (2 * Hc));
        int hstride = (t == 0) ? Hc : TYc * 2 * Hc;
        const float* cp = (t & 1) ? dc1 : dc0;
        float* cn = (t & 1) ? dc0 : dc1;
        k_dec_step<<<dim3(Hc / 64, Bc), 256, 0, stream>>>(gd, w_hh_d, hprev, hstride, cp, cn, outH, t);
        k_attn<<<Bc, 128, 0, stream>>>(hid, outH, t);
    }

    // logits = outH @ W_out^T + b_out
    const int nW = Vc * 2 * Hc;           // 32.768M
    const int nA = Bc * TYc * 2 * Hc;     // 2.097M
    size_t need = ((size_t)nW + nA) * sizeof(u16);
    if (ws_size >= need) {
        u16* Wb = (u16*)d_ws;
        u16* Ab = Wb + nW;
        k_cast<<<((nW + nA) / 4 + 255) / 256, 256, 0, stream>>>(W_out, outH, Wb, Ab, nW, nA);
        k_gemm_bf16<<<dim3(Vc / 128, Bc * TYc / 128), 256, 0, stream>>>(Ab, Wb, b_out, logp, Bc * TYc, Vc, 2 * Hc);
    } else {
        k_gemm_nt<<<dim3(Vc / 64, Bc * TYc / 64), 256, 0, stream>>>(outH, W_out, b_out, nullptr, logp, Bc * TYc, Vc, 2 * Hc);
    }
    k_logsm<<<Bc * TYc, 256, 0, stream>>>(logp);
}